// Round 6
// baseline (31.642 us; speedup 1.0000x reference)
//
#include <hip/hip_runtime.h>
#include <math.h>

#define NB 2
#define NN 512
#define DD 128
#define LOG2E 1.4426950408889634f

typedef unsigned long long ull;

__device__ __forceinline__ float exp2_hw(float x) {
    float r; asm("v_exp_f32 %0, %1" : "=v"(r) : "v"(x)); return r;
}
__device__ __forceinline__ float silu_f(float x) {
    float e = exp2_hw(-LOG2E * x);
    return x * __builtin_amdgcn_rcpf(1.0f + e);
}

// ---------------------------------------------------------------------------
// K1: node GEMM. 256 blocks x 4 rows, 256 threads (c=tid&127, h=tid>>7).
// 12 FMA per weight load in phase A (4 rows x 3 matrices). Weight traffic
// 256 blocks x 256KB = 66 MB from L2 (~2 us).
// Outputs: scalar_out (d_out), base_ws + vf3_ws (workspace).
// ---------------------------------------------------------------------------
__global__ __launch_bounds__(256) void k_node(
    const float* __restrict__ nf,
    const float* __restrict__ Ws1, const float* __restrict__ bs1,
    const float* __restrict__ Ws2, const float* __restrict__ bs2,
    const float* __restrict__ Wv1, const float* __restrict__ bv1,
    const float* __restrict__ Wv2, const float* __restrict__ bv2,
    const float* __restrict__ Wa1, const float* __restrict__ ba1,
    float* __restrict__ scalar_out,
    float* __restrict__ base_out,
    float* __restrict__ vf3_out)
{
    __shared__ float4 s_nf4[DD];           // 4 rows packed per feature
    __shared__ float  s_part[3][2][4][DD]; // [mat][khalf][row][col] partials
    __shared__ float4 s_hs4[DD];
    __shared__ float4 s_hv4[DD];
    __shared__ float  s_vp[96];

    const int tid = threadIdx.x;
    const int c   = tid & 127;
    const int h   = tid >> 7;
    const int r0  = blockIdx.x * 4;

    if (tid < DD) {
        float4 v;
        v.x = nf[(r0 + 0) * DD + tid];
        v.y = nf[(r0 + 1) * DD + tid];
        v.z = nf[(r0 + 2) * DD + tid];
        v.w = nf[(r0 + 3) * DD + tid];
        s_nf4[tid] = v;
    }
    __syncthreads();

    // ---- phase A: Ws1 / Wv1 / Wa1 fused, split-k over h ----
    float aS[4] = {0,0,0,0}, aV[4] = {0,0,0,0}, aA[4] = {0,0,0,0};
    const int k0 = h * 64;
    #pragma unroll 4
    for (int kk = 0; kk < 64; ++kk) {
        const int k = k0 + kk;
        float4 x = s_nf4[k];
        float w1 = Ws1[k * DD + c];
        float w2 = Wv1[k * DD + c];
        float w3 = Wa1[k * DD + c];
        aS[0] = fmaf(x.x, w1, aS[0]); aS[1] = fmaf(x.y, w1, aS[1]);
        aS[2] = fmaf(x.z, w1, aS[2]); aS[3] = fmaf(x.w, w1, aS[3]);
        aV[0] = fmaf(x.x, w2, aV[0]); aV[1] = fmaf(x.y, w2, aV[1]);
        aV[2] = fmaf(x.z, w2, aV[2]); aV[3] = fmaf(x.w, w2, aV[3]);
        aA[0] = fmaf(x.x, w3, aA[0]); aA[1] = fmaf(x.y, w3, aA[1]);
        aA[2] = fmaf(x.z, w3, aA[2]); aA[3] = fmaf(x.w, w3, aA[3]);
    }
    #pragma unroll
    for (int r = 0; r < 4; ++r) {
        s_part[0][h][r][c] = aS[r];
        s_part[1][h][r][c] = aV[r];
        s_part[2][h][r][c] = aA[r];
    }
    __syncthreads();

    if (tid < DD) {
        float hs[4], hv[4];
        #pragma unroll
        for (int r = 0; r < 4; ++r) {
            float vs = s_part[0][0][r][tid] + s_part[0][1][r][tid] + bs1[tid];
            float vv = s_part[1][0][r][tid] + s_part[1][1][r][tid] + bv1[tid];
            float va = s_part[2][0][r][tid] + s_part[2][1][r][tid] + ba1[tid];
            base_out[(r0 + r) * DD + tid] = va;
            hs[r] = silu_f(vs);
            hv[r] = silu_f(vv);
        }
        s_hs4[tid] = make_float4(hs[0], hs[1], hs[2], hs[3]);
        s_hv4[tid] = make_float4(hv[0], hv[1], hv[2], hv[3]);
    }
    __syncthreads();

    // ---- phase B: Ws2 @ hs (split-k) ----
    float aB[4] = {0,0,0,0};
    #pragma unroll 4
    for (int kk = 0; kk < 64; ++kk) {
        const int k = k0 + kk;
        float4 x = s_hs4[k];
        float w = Ws2[k * DD + c];
        aB[0] = fmaf(x.x, w, aB[0]); aB[1] = fmaf(x.y, w, aB[1]);
        aB[2] = fmaf(x.z, w, aB[2]); aB[3] = fmaf(x.w, w, aB[3]);
    }
    #pragma unroll
    for (int r = 0; r < 4; ++r) s_part[0][h][r][c] = aB[r];

    // ---- vf3 partials: 96 threads, (kq8, col, row) ----
    if (tid >= 128 && tid < 224) {
        const int idx = tid - 128;
        const int kq8 = idx / 12;
        const int rem = idx % 12;
        const int row = rem & 3;
        const int col = rem >> 2;        // 0..2
        const float* hv = (const float*)s_hv4;   // [k*4 + row]
        float vp = 0.f;
        #pragma unroll
        for (int u = 0; u < 16; ++u) {
            const int k = kq8 * 16 + u;
            vp = fmaf(hv[k * 4 + row], Wv2[k * DD + col], vp);
        }
        s_vp[idx] = vp;
    }
    __syncthreads();

    if (tid < DD) {
        #pragma unroll
        for (int r = 0; r < 4; ++r)
            scalar_out[(r0 + r) * DD + tid] =
                s_part[0][0][r][tid] + s_part[0][1][r][tid] + bs2[tid];
    }
    if (tid < 12) {
        const int row = tid & 3;
        const int col = tid >> 2;
        float v = bv2[col];
        #pragma unroll
        for (int q8 = 0; q8 < 8; ++q8) v += s_vp[q8 * 12 + (col << 2) + row];
        vf3_out[(r0 + row) * 3 + col] = v;
    }
}

// ---------------------------------------------------------------------------
// K2: attention. 1024 blocks x 128 threads (2 waves), 4 compacted rounds per
// thread. The 5 LDS b128 reads per t4 are hoisted once per wave and serve up
// to 16 elements; nact/nr live in SGPRs (readfirstlane) so inactive rounds
// are skipped by scalar branch.
// ---------------------------------------------------------------------------
#define UPD(P, Ae, r)                                                        \
    { float pre = fmaf(f3[r], P.w, fmaf(f2[r], P.z, fmaf(f1[r], P.y, P.x))); \
      float e   = exp2_hw(pre);                                              \
      float rc  = __builtin_amdgcn_rcpf(1.0f + e);                           \
      acc[r]    = fmaf(pre * Ae, rc, acc[r]); }

__global__ __launch_bounds__(128) void k_attn(
    const float* __restrict__ coords,
    const int*   __restrict__ mask,
    const float* __restrict__ Wa1,
    const float* __restrict__ Wa2,
    const float* __restrict__ ba2p,
    const float* __restrict__ base,
    const float* __restrict__ vf3,
    float* __restrict__ vec_out)
{
    __shared__ float4 s_pk[DD];          // (-l2e*base, -l2e*w0, -l2e*w1, -l2e*w2)
    __shared__ float  s_am[DD];          // -Wa2
    __shared__ short  s_act[NN];
    __shared__ int    s_cnt8[8], s_off8[8], s_nactS;
    __shared__ float  s_red[2], s_red2[2][4];

    const int row  = blockIdx.x;
    const int b    = row >> 9;
    const int tid  = threadIdx.x;        // 0..127
    const int lane = tid & 63;
    const int wid  = tid >> 6;           // 0..1

    {
        float4 p;
        p.x = -LOG2E * base[row * DD + tid];
        p.y = -LOG2E * Wa1[128 * DD + tid];
        p.z = -LOG2E * Wa1[129 * DD + tid];
        p.w = -LOG2E * Wa1[130 * DD + tid];
        s_pk[tid] = p;
        s_am[tid] = -Wa2[tid];
    }

    // ---- deterministic compaction over 4 chunks of 128 ----
    const int* mrow = mask + (size_t)row * NN;
    bool m[4]; ull bal[4];
    #pragma unroll
    for (int r = 0; r < 4; ++r) {
        m[r]   = (mrow[tid + 128 * r] != 0);
        bal[r] = __ballot(m[r]);
        if (lane == 0) s_cnt8[2 * r + wid] = __popcll(bal[r]);
    }
    __syncthreads();
    if (tid == 0) {
        int a = 0;
        #pragma unroll
        for (int q = 0; q < 8; ++q) { s_off8[q] = a; a += s_cnt8[q]; }
        s_nactS = a;
    }
    __syncthreads();
    {
        const ull lm = (1ull << lane) - 1ull;
        #pragma unroll
        for (int r = 0; r < 4; ++r)
            if (m[r]) s_act[s_off8[2 * r + wid] + __popcll(bal[r] & lm)]
                        = (short)(tid + 128 * r);
    }
    __syncthreads();

    const int nact = __builtin_amdgcn_readfirstlane(s_nactS);
    const int nr   = (nact + 127) >> 7;          // active rounds (SGPR)

    const float ba2l = ba2p[0] * LOG2E;
    const float xi0 = coords[row * 3 + 0];
    const float xi1 = coords[row * 3 + 1];
    const float xi2 = coords[row * 3 + 2];
    const float* cb = coords + (size_t)b * NN * 3;

    float dx[4], dy[4], dz[4], f1[4], f2[4], f3[4], acc[4];
    bool  act[4];

    #pragma unroll
    for (int r = 0; r < 4; ++r) {
        acc[r] = ba2l; act[r] = false;
        dx[r] = dy[r] = dz[r] = f1[r] = f2[r] = f3[r] = 0.f;
        if (r < nr) {
            const int a = tid + 128 * r;
            act[r] = (a < nact);
            const int j = ((int)s_act[act[r] ? a : 0]) & (NN - 1);
            dx[r] = xi0 - cb[j * 3 + 0];
            dy[r] = xi1 - cb[j * 3 + 1];
            dz[r] = xi2 - cb[j * 3 + 2];
            float d2 = fmaf(dx[r], dx[r], fmaf(dy[r], dy[r], dz[r] * dz[r]));
            float d  = sqrtf(d2);
            f1[r] = d;
            float x  = d + 1e-6f;
            float rc = __builtin_amdgcn_rcpf(x);
            f2[r] = rc * fmaf(-x, rc, 2.0f);     // Newton: 1/(d+1e-6)
            f3[r] = exp2_hw(-LOG2E * d);         // exp(-d)
        }
    }

    // ---- pass 1: t4-outer, rounds-inner; 5 LDS reads serve 4*nr elements --
    const float4* A4 = (const float4*)s_am;
    for (int t4 = 0; t4 < DD / 4; ++t4) {
        float4 A  = A4[t4];
        float4 P0 = s_pk[4 * t4 + 0];
        float4 P1 = s_pk[4 * t4 + 1];
        float4 P2 = s_pk[4 * t4 + 2];
        float4 P3 = s_pk[4 * t4 + 3];
        #pragma unroll
        for (int r = 0; r < 4; ++r) {
            if (r < nr) {
                UPD(P0, A.x, r); UPD(P1, A.y, r);
                UPD(P2, A.z, r); UPD(P3, A.w, r);
            }
        }
    }

    // ---- block max ----
    float mloc = -__builtin_inff();
    #pragma unroll
    for (int r = 0; r < 4; ++r)
        if (r < nr) mloc = fmaxf(mloc, act[r] ? acc[r] : -__builtin_inff());
    #pragma unroll
    for (int ofs = 32; ofs >= 1; ofs >>= 1) mloc = fmaxf(mloc, __shfl_xor(mloc, ofs));
    if (lane == 0) s_red[wid] = mloc;
    __syncthreads();
    const float mx = fmaxf(s_red[0], s_red[1]);

    // ---- pass 2: exp + weighted diff (registers only) ----
    float es = 0.f, wx = 0.f, wy = 0.f, wz = 0.f;
    #pragma unroll
    for (int r = 0; r < 4; ++r) {
        if (r < nr && act[r]) {
            float e = exp2_hw(acc[r] - mx);
            es += e;
            wx = fmaf(e, dx[r], wx);
            wy = fmaf(e, dy[r], wy);
            wz = fmaf(e, dz[r], wz);
        }
    }
    #pragma unroll
    for (int ofs = 32; ofs >= 1; ofs >>= 1) {
        es += __shfl_xor(es, ofs);
        wx += __shfl_xor(wx, ofs);
        wy += __shfl_xor(wy, ofs);
        wz += __shfl_xor(wz, ofs);
    }
    if (lane == 0) {
        s_red2[wid][0] = es; s_red2[wid][1] = wx;
        s_red2[wid][2] = wy; s_red2[wid][3] = wz;
    }
    __syncthreads();

    if (tid < 3) {
        float tot = s_red2[0][0] + s_red2[1][0];
        float num = s_red2[0][1 + tid] + s_red2[1][1 + tid];
        vec_out[row * 3 + tid] = (num / tot) * vf3[row * 3 + tid];
    }
}

extern "C" void kernel_launch(void* const* d_in, const int* in_sizes, int n_in,
                              void* d_out, int out_size, void* d_ws, size_t ws_size,
                              hipStream_t stream) {
    const float* nf     = (const float*)d_in[0];
    const float* coords = (const float*)d_in[1];
    const int*   mask   = (const int*)  d_in[2];
    const float* Ws1 = (const float*)d_in[3];  const float* bs1 = (const float*)d_in[4];
    const float* Ws2 = (const float*)d_in[5];  const float* bs2 = (const float*)d_in[6];
    const float* Wv1 = (const float*)d_in[7];  const float* bv1 = (const float*)d_in[8];
    const float* Wv2 = (const float*)d_in[9];  const float* bv2 = (const float*)d_in[10];
    const float* Wa1 = (const float*)d_in[11]; const float* ba1 = (const float*)d_in[12];
    const float* Wa2 = (const float*)d_in[13]; const float* ba2 = (const float*)d_in[14];

    float* scalar_out = (float*)d_out;                       // [NB*NN*DD]
    float* vec_out    = (float*)d_out + NB * NN * DD;        // [NB*NN*3]
    float* base_ws    = (float*)d_ws;                        // [NB*NN*DD]
    float* vf3_ws     = (float*)d_ws + NB * NN * DD;         // [NB*NN*3]

    hipLaunchKernelGGL(k_node, dim3(NB * NN / 4), dim3(256), 0, stream,
                       nf, Ws1, bs1, Ws2, bs2, Wv1, bv1, Wv2, bv2, Wa1, ba1,
                       scalar_out, base_ws, vf3_ws);
    hipLaunchKernelGGL(k_attn, dim3(NB * NN), dim3(128), 0, stream,
                       coords, mask, Wa1, Wa2, ba2, base_ws, vf3_ws, vec_out);
}

// Round 7
// 27.827 us; speedup vs baseline: 1.1371x; 1.1371x over previous
//
#include <hip/hip_runtime.h>
#include <math.h>

#define NB 2
#define NN 512
#define DD 128
#define LOG2E 1.4426950408889634f

typedef unsigned long long ull;

__device__ __forceinline__ float exp2_hw(float x) {
    float r; asm("v_exp_f32 %0, %1" : "=v"(r) : "v"(x)); return r;
}
__device__ __forceinline__ float silu_f(float x) {
    float e = exp2_hw(-LOG2E * x);
    return x * __builtin_amdgcn_rcpf(1.0f + e);
}

// ---------------------------------------------------------------------------
// One kernel, 1024 blocks (one per (b,i) row), 256 threads, 16 waves/CU.
// R5 structure + (a) t4-outer pass-1 so 5 LDS b128 reads serve 8 elements,
// (b) float4 LDS reads in the GEMV phases, (c) wave-uniform skip of the
// mostly-empty second round. Deterministic compaction, no atomics.
// ---------------------------------------------------------------------------
#define UPD(P, Ae, ff1, ff2, ff3, accv)                                       \
    { float pre = fmaf(ff3, P.w, fmaf(ff2, P.z, fmaf(ff1, P.y, P.x)));        \
      float e   = exp2_hw(pre);                                               \
      float rc  = __builtin_amdgcn_rcpf(1.0f + e);                            \
      accv      = fmaf(pre * Ae, rc, accv); }

__global__ __launch_bounds__(256) void k_all(
    const float* __restrict__ nf,
    const float* __restrict__ coords,
    const int*   __restrict__ mask,
    const float* __restrict__ Ws1, const float* __restrict__ bs1,
    const float* __restrict__ Ws2, const float* __restrict__ bs2,
    const float* __restrict__ Wv1, const float* __restrict__ bv1,
    const float* __restrict__ Wv2, const float* __restrict__ bv2,
    const float* __restrict__ Wa1, const float* __restrict__ ba1,
    const float* __restrict__ Wa2, const float* __restrict__ ba2p,
    float* __restrict__ scalar_out,
    float* __restrict__ vec_out)
{
    __shared__ __align__(16) float s_nf[DD];
    __shared__ __align__(16) float s_hs[DD];
    __shared__ __align__(16) float s_hv[DD];
    __shared__ __align__(16) float s_am[DD];
    __shared__ float  s_part[3][256];
    __shared__ float4 s_pk[DD];          // (-l2e*base, -l2e*w0, -l2e*w1, -l2e*w2)
    __shared__ short  s_act[NN];
    __shared__ int    s_cnt8[8], s_off8[8], s_nactS;
    __shared__ float  s_red[4], s_red2[4][4];

    const int row  = blockIdx.x;         // b*NN + i
    const int b    = row >> 9;
    const int tid  = threadIdx.x;
    const int lane = tid & 63;
    const int wid  = tid >> 6;
    const int c    = tid & 127;
    const int h    = tid >> 7;

    if (tid < DD) s_nf[tid] = nf[row * DD + tid];
    const int* mrow = mask + (size_t)row * NN;
    const bool m0 = (mrow[tid]       != 0);
    const bool m1 = (mrow[tid + 256] != 0);
    const ull  bal0 = __ballot(m0);
    const ull  bal1 = __ballot(m1);
    if (lane == 0) {
        s_cnt8[wid]     = __popcll(bal0);
        s_cnt8[4 + wid] = __popcll(bal1);
    }
    __syncthreads();   // s_nf + s_cnt8 ready

    if (tid == 0) {
        int a = 0;
        #pragma unroll
        for (int q = 0; q < 8; ++q) { s_off8[q] = a; a += s_cnt8[q]; }
        s_nactS = a;
    }
    // ---- phase A: fused layer-1 GEMVs (Ws1/Wv1/Wa1), split-k, float4 LDS ----
    {
        float ps = 0.f, pv = 0.f, pa = 0.f;
        const float4* nf4 = (const float4*)s_nf;
        const int kq0 = h * 16;
        #pragma unroll 4
        for (int kk = 0; kk < 16; ++kk) {
            float4 x = nf4[kq0 + kk];
            const int k = (kq0 + kk) * 4;
            ps = fmaf(x.x, Ws1[(k+0)*DD + c], ps);
            ps = fmaf(x.y, Ws1[(k+1)*DD + c], ps);
            ps = fmaf(x.z, Ws1[(k+2)*DD + c], ps);
            ps = fmaf(x.w, Ws1[(k+3)*DD + c], ps);
            pv = fmaf(x.x, Wv1[(k+0)*DD + c], pv);
            pv = fmaf(x.y, Wv1[(k+1)*DD + c], pv);
            pv = fmaf(x.z, Wv1[(k+2)*DD + c], pv);
            pv = fmaf(x.w, Wv1[(k+3)*DD + c], pv);
            pa = fmaf(x.x, Wa1[(k+0)*DD + c], pa);
            pa = fmaf(x.y, Wa1[(k+1)*DD + c], pa);
            pa = fmaf(x.z, Wa1[(k+2)*DD + c], pa);
            pa = fmaf(x.w, Wa1[(k+3)*DD + c], pa);
        }
        s_part[0][tid] = ps;
        s_part[1][tid] = pv;
        s_part[2][tid] = pa;
    }
    __syncthreads();   // partials + s_off8 ready

    if (tid < DD) {
        s_hs[tid] = silu_f(s_part[0][tid] + s_part[0][128 + tid] + bs1[tid]);
        s_hv[tid] = silu_f(s_part[1][tid] + s_part[1][128 + tid] + bv1[tid]);
        float base = s_part[2][tid] + s_part[2][128 + tid] + ba1[tid];
        float4 p;
        p.x = -LOG2E * base;
        p.y = -LOG2E * Wa1[128 * DD + tid];
        p.z = -LOG2E * Wa1[129 * DD + tid];
        p.w = -LOG2E * Wa1[130 * DD + tid];
        s_pk[tid] = p;
        s_am[tid] = -Wa2[tid];
    }
    {
        const ull lm = (1ull << lane) - 1ull;
        if (m0) s_act[s_off8[wid]     + __popcll(bal0 & lm)] = (short)tid;
        if (m1) s_act[s_off8[4 + wid] + __popcll(bal1 & lm)] = (short)(tid + 256);
    }
    __syncthreads();   // s_hs/s_hv/s_pk/s_am/s_act ready; s_part free

    // ---- phase B: Ws2 GEMV (float4 LDS) + vf3 partials ----
    {
        float pb = 0.f;
        const float4* hs4 = (const float4*)s_hs;
        const int kq0 = h * 16;
        #pragma unroll 4
        for (int kk = 0; kk < 16; ++kk) {
            float4 x = hs4[kq0 + kk];
            const int k = (kq0 + kk) * 4;
            pb = fmaf(x.x, Ws2[(k+0)*DD + c], pb);
            pb = fmaf(x.y, Ws2[(k+1)*DD + c], pb);
            pb = fmaf(x.z, Ws2[(k+2)*DD + c], pb);
            pb = fmaf(x.w, Ws2[(k+3)*DD + c], pb);
        }
        s_part[0][tid] = pb;
    }
    if (tid >= 128 && tid < 224) {
        const int idx = tid - 128;
        const int col = idx >> 5;        // 0..2
        const int kq  = idx & 31;        // k = 4*kq .. 4*kq+3
        float vp = 0.f;
        #pragma unroll
        for (int u = 0; u < 4; ++u) {
            const int k = 4 * kq + u;
            vp = fmaf(s_hv[k], Wv2[k * DD + col], vp);
        }
        s_part[1][tid] = vp;
    }

    // ---- attention pass 1 (same region: no dependence on s_part) ----
    const int nact = __builtin_amdgcn_readfirstlane(s_nactS);
    const bool act0 = (tid < nact);
    const bool act1 = (tid + 256 < nact);
    const bool w_has1 = ((tid & ~63) + 256) < nact;   // wave-uniform

    const float ba2l = ba2p[0] * LOG2E;
    const float xi0 = coords[row * 3 + 0];
    const float xi1 = coords[row * 3 + 1];
    const float xi2 = coords[row * 3 + 2];
    const float* cb = coords + (size_t)b * NN * 3;

    float dx0 = 0.f, dy0 = 0.f, dz0 = 0.f, f1_0 = 0.f, f2_0 = 0.f, f3_0 = 0.f;
    float dx1 = 0.f, dy1 = 0.f, dz1 = 0.f, f1_1 = 0.f, f2_1 = 0.f, f3_1 = 0.f;
    float acc0 = ba2l, acc1 = ba2l;

    {
        const int j = ((int)s_act[act0 ? tid : 0]) & (NN - 1);
        dx0 = xi0 - cb[j * 3 + 0];
        dy0 = xi1 - cb[j * 3 + 1];
        dz0 = xi2 - cb[j * 3 + 2];
        float d2 = fmaf(dx0, dx0, fmaf(dy0, dy0, dz0 * dz0));
        float d  = sqrtf(d2);
        f1_0 = d;
        float x  = d + 1e-6f;
        float rc = __builtin_amdgcn_rcpf(x);
        f2_0 = rc * fmaf(-x, rc, 2.0f);
        f3_0 = exp2_hw(-LOG2E * d);
    }
    if (w_has1) {
        const int j = ((int)s_act[act1 ? tid + 256 : 0]) & (NN - 1);
        dx1 = xi0 - cb[j * 3 + 0];
        dy1 = xi1 - cb[j * 3 + 1];
        dz1 = xi2 - cb[j * 3 + 2];
        float d2 = fmaf(dx1, dx1, fmaf(dy1, dy1, dz1 * dz1));
        float d  = sqrtf(d2);
        f1_1 = d;
        float x  = d + 1e-6f;
        float rc = __builtin_amdgcn_rcpf(x);
        f2_1 = rc * fmaf(-x, rc, 2.0f);
        f3_1 = exp2_hw(-LOG2E * d);
    }

    const float4* A4 = (const float4*)s_am;
    for (int t4 = 0; t4 < DD / 4; ++t4) {
        float4 A  = A4[t4];
        float4 P0 = s_pk[4 * t4 + 0];
        float4 P1 = s_pk[4 * t4 + 1];
        float4 P2 = s_pk[4 * t4 + 2];
        float4 P3 = s_pk[4 * t4 + 3];
        UPD(P0, A.x, f1_0, f2_0, f3_0, acc0);
        UPD(P1, A.y, f1_0, f2_0, f3_0, acc0);
        UPD(P2, A.z, f1_0, f2_0, f3_0, acc0);
        UPD(P3, A.w, f1_0, f2_0, f3_0, acc0);
        if (w_has1) {
            UPD(P0, A.x, f1_1, f2_1, f3_1, acc1);
            UPD(P1, A.y, f1_1, f2_1, f3_1, acc1);
            UPD(P2, A.z, f1_1, f2_1, f3_1, acc1);
            UPD(P3, A.w, f1_1, f2_1, f3_1, acc1);
        }
    }
    __syncthreads();   // s_part (phase B) ready

    if (tid < DD) {
        scalar_out[row * DD + tid] = s_part[0][tid] + s_part[0][128 + tid] + bs2[tid];
    }
    float vf_col = 0.f;
    if (tid < 3) {
        float v = bv2[tid];
        const float* pp = &s_part[1][128 + tid * 32];
        for (int r = 0; r < 32; ++r) v += pp[r];
        vf_col = v;
    }

    // ---- block max ----
    float mloc = -__builtin_inff();
    if (act0) mloc = acc0;
    if (act1) mloc = fmaxf(mloc, acc1);
    #pragma unroll
    for (int ofs = 32; ofs >= 1; ofs >>= 1) mloc = fmaxf(mloc, __shfl_xor(mloc, ofs));
    if (lane == 0) s_red[wid] = mloc;
    __syncthreads();
    const float mx = fmaxf(fmaxf(s_red[0], s_red[1]), fmaxf(s_red[2], s_red[3]));

    // ---- pass 2: exp + weighted diff (registers only) ----
    float es = 0.f, wx = 0.f, wy = 0.f, wz = 0.f;
    if (act0) {
        float e = exp2_hw(acc0 - mx);
        es += e; wx = fmaf(e, dx0, wx); wy = fmaf(e, dy0, wy); wz = fmaf(e, dz0, wz);
    }
    if (w_has1 && act1) {
        float e = exp2_hw(acc1 - mx);
        es += e; wx = fmaf(e, dx1, wx); wy = fmaf(e, dy1, wy); wz = fmaf(e, dz1, wz);
    }
    #pragma unroll
    for (int ofs = 32; ofs >= 1; ofs >>= 1) {
        es += __shfl_xor(es, ofs);
        wx += __shfl_xor(wx, ofs);
        wy += __shfl_xor(wy, ofs);
        wz += __shfl_xor(wz, ofs);
    }
    if (lane == 0) {
        s_red2[wid][0] = es; s_red2[wid][1] = wx;
        s_red2[wid][2] = wy; s_red2[wid][3] = wz;
    }
    __syncthreads();

    if (tid < 3) {
        float tot = s_red2[0][0] + s_red2[1][0] + s_red2[2][0] + s_red2[3][0];
        float num = s_red2[0][1+tid] + s_red2[1][1+tid] + s_red2[2][1+tid] + s_red2[3][1+tid];
        vec_out[row * 3 + tid] = (num / tot) * vf_col;
    }
}

extern "C" void kernel_launch(void* const* d_in, const int* in_sizes, int n_in,
                              void* d_out, int out_size, void* d_ws, size_t ws_size,
                              hipStream_t stream) {
    const float* nf     = (const float*)d_in[0];
    const float* coords = (const float*)d_in[1];
    const int*   mask   = (const int*)  d_in[2];
    const float* Ws1 = (const float*)d_in[3];  const float* bs1 = (const float*)d_in[4];
    const float* Ws2 = (const float*)d_in[5];  const float* bs2 = (const float*)d_in[6];
    const float* Wv1 = (const float*)d_in[7];  const float* bv1 = (const float*)d_in[8];
    const float* Wv2 = (const float*)d_in[9];  const float* bv2 = (const float*)d_in[10];
    const float* Wa1 = (const float*)d_in[11]; const float* ba1 = (const float*)d_in[12];
    const float* Wa2 = (const float*)d_in[13]; const float* ba2 = (const float*)d_in[14];

    float* scalar_out = (float*)d_out;                   // [NB*NN*DD]
    float* vec_out    = (float*)d_out + NB * NN * DD;    // [NB*NN*3]

    hipLaunchKernelGGL(k_all, dim3(NB * NN), dim3(256), 0, stream,
                       nf, coords, mask,
                       Ws1, bs1, Ws2, bs2, Wv1, bv1, Wv2, bv2,
                       Wa1, ba1, Wa2, ba2,
                       scalar_out, vec_out);
}